// Round 6
// baseline (795.828 us; speedup 1.0000x reference)
//
#include <hip/hip_runtime.h>
#include <stdint.h>

// Problem constants (from reference setup_inputs) — ALL TENSORS ARE FLOAT32.
#define T_STEPS 100
#define BATCH   65536
#define NI      2
#define NH      10
#define NO      4
#define KCH     5    // time chunks; block's chunk = blockIdx.x % KCH
#define TC      20   // steps per chunk; KCH*TC == T_STEPS
#define GS      2    // steps per staging group (LDS granularity)
#define GPC     (TC / GS)   // 10 groups per chunk

typedef float vf2 __attribute__((ext_vector_type(2)));
typedef float vf4 __attribute__((ext_vector_type(4)));

// Uniform (wave-invariant) load forced into an SGPR: keeps the 74 weight
// scalars out of the VGPR budget (128-VGPR cap at (256,4); no spills).
__device__ __forceinline__ float uload(const float* p) {
    return __uint_as_float((uint32_t)__builtin_amdgcn_readfirstlane((int)__float_as_uint(*p)));
}

#define LOAD_WEIGHTS                                                        \
    float w1[NH][NI], bb1[NH], w2[NO][NH], bb2[NO];                         \
    _Pragma("unroll") for (int h = 0; h < NH; ++h) {                        \
        w1[h][0] = uload(&W1[h * NI + 0]);                                  \
        w1[h][1] = uload(&W1[h * NI + 1]);                                  \
        bb1[h]   = uload(&b1[h]);                                           \
    }                                                                       \
    _Pragma("unroll") for (int o = 0; o < NO; ++o) {                        \
        _Pragma("unroll") for (int h = 0; h < NH; ++h)                      \
            w2[o][h] = uload(&W2[o * NH + h]);                              \
        bb2[o] = uload(&b2[o]);                                             \
    }

// One LIF timestep for both layers. EXACT arithmetic order of the
// harness-verified kernel (fmaf ascending-k, 0.5*m exact, reset exact):
// any change here changes absmax vs the reference.
__device__ __forceinline__ void lif_step(
    const float x0, const float x1,
    const float w1[NH][NI], const float bb1[NH],
    const float w2[NO][NH], const float bb2[NO],
    float m1[NH], float m2[NO], float spk1[NH], float spk2[NO])
{
#pragma unroll
    for (int h = 0; h < NH; ++h) {
        float syn   = __builtin_fmaf(x1, w1[h][1], x0 * w1[h][0]) + bb1[h];
        float reset = (m1[h] > 1.0f) ? 1.0f : 0.0f;   // pre-update membrane, detached
        float m     = 0.5f * m1[h] + syn;
        m           = m - reset;
        m1[h]       = m;
        spk1[h]     = ((m - 1.0f) > 0.0f) ? 1.0f : 0.0f;
    }
#pragma unroll
    for (int o = 0; o < NO; ++o) {
        float acc = spk1[0] * w2[o][0];
#pragma unroll
        for (int h = 1; h < NH; ++h) acc = __builtin_fmaf(spk1[h], w2[o][h], acc);
        float syn   = acc + bb2[o];
        float reset = (m2[o] > 1.0f) ? 1.0f : 0.0f;
        float m     = 0.5f * m2[o] + syn;
        m           = m - reset;
        m2[o]       = m;
        spk2[o]     = ((m - 1.0f) > 0.0f) ? 1.0f : 0.0f;
    }
}

// ---------------------------------------------------------------------------
// Single fused kernel, nontemporal stores + 4 blocks/CU.
//
// Block = (chunk k, batch slice bb). Phase 1: store-free recompute of steps
// [0, k*TC) — x re-reads served by L3 (52 MB << 256 MB), which NT output
// stores no longer evict. Phase 2: per group of GS=2 steps: compute into
// 40 KiB LDS staging (spk2/mem2 in registers), then a streaming bulk-store
// pass of coalesced NT wave-stores (>=512B contiguous full lines per
// instruction — no partial-burst risk, no L2 write-allocate sweep).
//
// Each wave reads back only its own lanes' staging rows -> wave-internal
// DS ordering suffices, no barriers at all. 16 waves/CU overlap the
// scan-VALU of late-k blocks with the store streams of early-k blocks.
// ---------------------------------------------------------------------------
__global__ __launch_bounds__(256, 4) void snn_fused(
    const float* __restrict__ x, const float* __restrict__ W1,
    const float* __restrict__ b1, const float* __restrict__ W2,
    const float* __restrict__ b2, float* __restrict__ out)
{
    LOAD_WEIGHTS;

    const int tid  = threadIdx.x;
    const int k    = blockIdx.x % KCH;         // chunk 0..4 (interleaved for CU mixing)
    const int bb   = blockIdx.x / KCH;         // batch block 0..255
    const int b    = bb * 256 + tid;
    const int w    = tid >> 6;
    const int lane = tid & 63;
    const int wb0  = bb * 256 + (w << 6);      // wave's first batch element

    const size_t sec = (size_t)T_STEPS * BATCH;
    float* o_spk1 = out;
    float* o_mem1 = out + sec * NH;
    float* o_spk2 = out + 2 * sec * NH;
    float* o_mem2 = out + 2 * sec * NH + sec * NO;

    const vf2* xp = (const vf2*)x + b;

    float m1[NH], m2[NO];
#pragma unroll
    for (int h = 0; h < NH; ++h) m1[h] = 0.0f;
#pragma unroll
    for (int o = 0; o < NO; ++o) m2[o] = 0.0f;

    const int Gscan = k * GPC;                 // store-free groups
    const int G     = Gscan + GPC;             // total groups (10..50)

    // x pipeline: current + next group (4-step lookahead, ~1500cy of compute
    // between issue and use at GS=2). All static indexing.
    vf2 xc[GS], xn[GS];
#pragma unroll
    for (int i = 0; i < GS; ++i) xc[i] = xp[(size_t)i * BATCH];
#pragma unroll
    for (int i = 0; i < GS; ++i) xn[i] = xp[(size_t)(GS + i) * BATCH];

    // Staging: 40 KiB -> 4 blocks/CU. Layout [step][elem][h] matches the
    // global [elem][h] order so the bulk pass is a linear copy.
    __shared__ float sA[GS][256][NH];          // spk1
    __shared__ float sB[GS][256][NH];          // mem1

    vf4 s2r[GS], m2r[GS];                      // spk2/mem2 register staging

    for (int g = 0; g < G; ++g) {
        if (g < Gscan) {
            // ---- scan: state update only, nothing emitted.
#pragma unroll
            for (int j = 0; j < GS; ++j) {
                float spk1[NH], spk2[NO];
                lif_step(xc[j].x, xc[j].y, w1, bb1, w2, bb2, m1, m2, spk1, spk2);
            }
        } else {
            // ---- compute phase: GS steps, outputs to LDS/regs only.
#pragma unroll
            for (int j = 0; j < GS; ++j) {
                float spk1[NH], spk2[NO];
                lif_step(xc[j].x, xc[j].y, w1, bb1, w2, bb2, m1, m2, spk1, spk2);
                vf2* qa = (vf2*)&sA[j][tid][0];
                vf2* qb = (vf2*)&sB[j][tid][0];
#pragma unroll
                for (int i = 0; i < NH / 2; ++i) {
                    vf2 vs; vs.x = spk1[2 * i]; vs.y = spk1[2 * i + 1];
                    vf2 vm; vm.x = m1[2 * i];   vm.y = m1[2 * i + 1];
                    qa[i] = vs;
                    qb[i] = vm;
                }
                vf4 v2; v2.x = spk2[0]; v2.y = spk2[1]; v2.z = spk2[2]; v2.w = spk2[3];
                vf4 vm2; vm2.x = m2[0]; vm2.y = m2[1]; vm2.z = m2[2]; vm2.w = m2[3];
                s2r[j] = v2;
                m2r[j] = vm2;
            }
            __builtin_amdgcn_wave_barrier();   // keep DS write/read program order

            // ---- bulk store phase: streaming NT stores, no intervening waits.
            const int t0g = k * TC + (g - Gscan) * GS;
#pragma unroll
            for (int j = 0; j < GS; ++j) {
                const int t = t0g + j;
                {   // spk1: wave's 2560B staging region -> contiguous global run
                    const float* ls = &sA[j][w * 64][0];
                    vf4 r0 = ((const vf4*)ls)[lane];
                    vf4 r1 = ((const vf4*)ls)[64 + lane];
                    vf2 r2 = ((const vf2*)ls)[256 + lane];
                    float* gd = o_spk1 + ((size_t)t * BATCH + wb0) * NH;
                    __builtin_nontemporal_store(r0, (vf4*)gd + lane);
                    __builtin_nontemporal_store(r1, (vf4*)gd + 64 + lane);
                    __builtin_nontemporal_store(r2, (vf2*)gd + 256 + lane);
                }
                {   // mem1
                    const float* ls = &sB[j][w * 64][0];
                    vf4 r0 = ((const vf4*)ls)[lane];
                    vf4 r1 = ((const vf4*)ls)[64 + lane];
                    vf2 r2 = ((const vf2*)ls)[256 + lane];
                    float* gd = o_mem1 + ((size_t)t * BATCH + wb0) * NH;
                    __builtin_nontemporal_store(r0, (vf4*)gd + lane);
                    __builtin_nontemporal_store(r1, (vf4*)gd + 64 + lane);
                    __builtin_nontemporal_store(r2, (vf2*)gd + 256 + lane);
                }
                // spk2/mem2: 16B/lane at 16B stride, 1024B/wave contiguous.
                __builtin_nontemporal_store(s2r[j], (vf4*)(o_spk2 + ((size_t)t * BATCH + b) * NO));
                __builtin_nontemporal_store(m2r[j], (vf4*)(o_mem2 + ((size_t)t * BATCH + b) * NO));
            }
            __builtin_amdgcn_wave_barrier();
        }

        // ---- advance x pipeline (guarded; max needed group is G-1).
#pragma unroll
        for (int i = 0; i < GS; ++i) xc[i] = xn[i];
        if (g + 2 < G) {
#pragma unroll
            for (int i = 0; i < GS; ++i)
                xn[i] = xp[(size_t)((g + 2) * GS + i) * BATCH];
        }
    }
}

extern "C" void kernel_launch(void* const* d_in, const int* in_sizes, int n_in,
                              void* d_out, int out_size, void* d_ws, size_t ws_size,
                              hipStream_t stream) {
    const float* x  = (const float*)d_in[0];
    const float* W1 = (const float*)d_in[1];
    const float* b1 = (const float*)d_in[2];
    const float* W2 = (const float*)d_in[3];
    const float* b2 = (const float*)d_in[4];
    float* out = (float*)d_out;

    // One dispatch: 1280 blocks (5 chunks x 256 batch-blocks, k-interleaved).
    snn_fused<<<(BATCH / 256) * KCH, 256, 0, stream>>>(x, W1, b1, W2, b2, out);
}

// Round 7
// 776.106 us; speedup vs baseline: 1.0254x; 1.0254x over previous
//
#include <hip/hip_runtime.h>
#include <stdint.h>

// Problem constants (from reference setup_inputs) — ALL TENSORS ARE FLOAT32.
#define T_STEPS 100
#define BATCH   65536
#define NI      2
#define NH      10
#define NO      4
#define KCH     10   // time chunks (parallelism over T in the output kernels)
#define TC      10   // steps per chunk; KCH*TC == T_STEPS

typedef float vf2 __attribute__((ext_vector_type(2)));
typedef float vf4 __attribute__((ext_vector_type(4)));

// Uniform (wave-invariant) load forced into an SGPR: keeps the 74 weight
// scalars out of the VGPR budget so the unrolled loops never spill.
__device__ __forceinline__ float uload(const float* p) {
    return __uint_as_float((uint32_t)__builtin_amdgcn_readfirstlane((int)__float_as_uint(*p)));
}

#define LOAD_WEIGHTS                                                        \
    float w1[NH][NI], bb1[NH], w2[NO][NH], bb2[NO];                         \
    _Pragma("unroll") for (int h = 0; h < NH; ++h) {                        \
        w1[h][0] = uload(&W1[h * NI + 0]);                                  \
        w1[h][1] = uload(&W1[h * NI + 1]);                                  \
        bb1[h]   = uload(&b1[h]);                                           \
    }                                                                       \
    _Pragma("unroll") for (int o = 0; o < NO; ++o) {                        \
        _Pragma("unroll") for (int h = 0; h < NH; ++h)                      \
            w2[o][h] = uload(&W2[o * NH + h]);                              \
        bb2[o] = uload(&b2[o]);                                             \
    }

// One LIF timestep for both layers. EXACT arithmetic order of the
// harness-verified kernel (fmaf ascending-k, 0.5*m exact, reset exact):
// any change here changes absmax vs the reference.
__device__ __forceinline__ void lif_step(
    const float x0, const float x1,
    const float w1[NH][NI], const float bb1[NH],
    const float w2[NO][NH], const float bb2[NO],
    float m1[NH], float m2[NO], float spk1[NH], float spk2[NO])
{
#pragma unroll
    for (int h = 0; h < NH; ++h) {
        float syn   = __builtin_fmaf(x1, w1[h][1], x0 * w1[h][0]) + bb1[h];
        float reset = (m1[h] > 1.0f) ? 1.0f : 0.0f;   // pre-update membrane, detached
        float m     = 0.5f * m1[h] + syn;
        m           = m - reset;
        m1[h]       = m;
        spk1[h]     = ((m - 1.0f) > 0.0f) ? 1.0f : 0.0f;
    }
#pragma unroll
    for (int o = 0; o < NO; ++o) {
        float acc = spk1[0] * w2[o][0];
#pragma unroll
        for (int h = 1; h < NH; ++h) acc = __builtin_fmaf(spk1[h], w2[o][h], acc);
        float syn   = acc + bb2[o];
        float reset = (m2[o] > 1.0f) ? 1.0f : 0.0f;
        float m     = 0.5f * m2[o] + syn;
        m           = m - reset;
        m2[o]       = m;
        spk2[o]     = ((m - 1.0f) > 0.0f) ? 1.0f : 0.0f;
    }
}

// ---------------------------------------------------------------------------
// Serial-scan body (one thread per element): runs all 100 steps, writes ONLY
// the checkpoint membrane rows (t = 9,19,...,89) — which are bitwise the
// mem1_rec/mem2_rec outputs at those t — directly into `out`.
// ---------------------------------------------------------------------------
__device__ __forceinline__ void ckpt_body(
    const int b, const float* __restrict__ x,
    const float w1[NH][NI], const float bb1[NH],
    const float w2[NO][NH], const float bb2[NO],
    float* __restrict__ out)
{
    float m1[NH], m2[NO];
#pragma unroll
    for (int h = 0; h < NH; ++h) m1[h] = 0.0f;
#pragma unroll
    for (int o = 0; o < NO; ++o) m2[o] = 0.0f;

    const size_t sec = (size_t)T_STEPS * BATCH;
    float* o_mem1 = out + sec * NH;
    float* o_mem2 = out + 2 * sec * NH + sec * NO;

    const vf2* xp = (const vf2*)x + b;
    vf2 xb[TC];                         // static-index rolling buffer, depth 10
#pragma unroll
    for (int j = 0; j < TC; ++j) xb[j] = xp[(size_t)j * BATCH];

    for (int tt = 0; tt < T_STEPS; tt += TC) {
#pragma unroll
        for (int j = 0; j < TC; ++j) {
            const int t = tt + j;
            const float x0 = xb[j].x;
            const float x1 = xb[j].y;
            if (t + TC < T_STEPS) xb[j] = xp[(size_t)(t + TC) * BATCH];

            float spk1[NH], spk2[NO];
            lif_step(x0, x1, w1, bb1, w2, bb2, m1, m2, spk1, spk2);

            if (j == TC - 1 && t + 1 < T_STEPS) {
                float* pm1 = o_mem1 + ((size_t)t * BATCH + b) * NH;
                vf2* q = (vf2*)pm1;
#pragma unroll
                for (int i = 0; i < NH / 2; ++i) {
                    vf2 v; v.x = m1[2 * i]; v.y = m1[2 * i + 1];
                    q[i] = v;
                }
                vf4 v2; v2.x = m2[0]; v2.y = m2[1]; v2.z = m2[2]; v2.w = m2[3];
                *(vf4*)(o_mem2 + ((size_t)t * BATCH + b) * NO) = v2;
            }
        }
    }
}

// ---------------------------------------------------------------------------
// Output-chunk body: replay TC=10 steps of one element from a bitwise-exact
// starting state (zeros for k==0, else checkpoint row t0-1) and write all
// outputs. NH-array stores go through a WAVE-LOCAL LDS transpose (no
// s_barrier needed: DS ops are in-order within a wave) so every global store
// is a fully-coalesced contiguous dwordx4/dwordx2 pass.
// ---------------------------------------------------------------------------
__device__ __forceinline__ void out_chunk(
    const int k, const int bb, const int tid,
    const float* __restrict__ x,
    const float w1[NH][NI], const float bb1[NH],
    const float w2[NO][NH], const float bb2[NO],
    float* __restrict__ out)
{
    const int b    = bb * 256 + tid;
    const int t0   = k * TC;
    const int w    = tid >> 6;
    const int lane = tid & 63;
    const int wb0  = bb * 256 + (w << 6);      // wave's first batch element

    const size_t sec = (size_t)T_STEPS * BATCH;
    float* o_spk1 = out;
    float* o_mem1 = out + sec * NH;
    float* o_spk2 = out + 2 * sec * NH;
    float* o_mem2 = out + 2 * sec * NH + sec * NO;

    // Issue all 10 x loads for this chunk up front (coalesced vf2).
    const vf2* xp = (const vf2*)x + b;
    vf2 xb[TC];
#pragma unroll
    for (int j = 0; j < TC; ++j) xb[j] = xp[(size_t)(t0 + j) * BATCH];

    float m1[NH], m2[NO];
    if (k == 0) {
#pragma unroll
        for (int h = 0; h < NH; ++h) m1[h] = 0.0f;
#pragma unroll
        for (int o = 0; o < NO; ++o) m2[o] = 0.0f;
    } else {
        const float* pm1 = o_mem1 + ((size_t)(t0 - 1) * BATCH + b) * NH;
#pragma unroll
        for (int i = 0; i < NH / 2; ++i) {
            vf2 v = ((const vf2*)pm1)[i];
            m1[2 * i] = v.x; m1[2 * i + 1] = v.y;
        }
        vf4 v2 = *(const vf4*)(o_mem2 + ((size_t)(t0 - 1) * BATCH + b) * NO);
        m2[0] = v2.x; m2[1] = v2.y; m2[2] = v2.z; m2[3] = v2.w;
    }

    // Per-wave staging: [wave][spk/mem][160 vf4] = 2560B per array per wave.
    __shared__ vf4 stage[4][2][160];           // 20480 B/block
    float* s_spk = (float*)&stage[w][0][0];
    float* s_mem = (float*)&stage[w][1][0];

#pragma unroll
    for (int j = 0; j < TC; ++j) {
        const int t = t0 + j;
        float spk1[NH], spk2[NO];
        lif_step(xb[j].x, xb[j].y, w1, bb1, w2, bb2, m1, m2, spk1, spk2);

        // Stage NH outputs into wave-local LDS (5x ds_write_b64 each).
        {
            vf2* qs = (vf2*)s_spk;
            vf2* qm = (vf2*)s_mem;
#pragma unroll
            for (int i = 0; i < NH / 2; ++i) {
                vf2 vs; vs.x = spk1[2 * i]; vs.y = spk1[2 * i + 1];
                vf2 vm; vm.x = m1[2 * i];   vm.y = m1[2 * i + 1];
                qs[lane * 5 + i] = vs;
                qm[lane * 5 + i] = vm;
            }
        }
        __builtin_amdgcn_wave_barrier();

        // Chunk-final mem rows (t = k*10+9, k<9) are written by the ckpt role
        // with bitwise-identical values — skip them (saves ~42 MB).
        const bool storeMem = (j < TC - 1) || (k == KCH - 1);

        // Coalesced store of the wave's 2560B spk1 region: 2x dwordx4 + 1x dwordx2.
        {
            float* g = o_spk1 + (size_t)t * BATCH * NH + (size_t)wb0 * NH;
            vf4* g4 = (vf4*)g;
            g4[lane]      = stage[w][0][lane];
            g4[64 + lane] = stage[w][0][64 + lane];
            ((vf2*)g)[256 + lane] = ((vf2*)s_spk)[256 + lane];
        }
        if (storeMem) {
            float* g = o_mem1 + (size_t)t * BATCH * NH + (size_t)wb0 * NH;
            vf4* g4 = (vf4*)g;
            g4[lane]      = stage[w][1][lane];
            g4[64 + lane] = stage[w][1][64 + lane];
            ((vf2*)g)[256 + lane] = ((vf2*)s_mem)[256 + lane];
        }
        __builtin_amdgcn_wave_barrier();

        // NO outputs: 16B/lane at 16B stride -> already fully coalesced.
        {
            vf4 vs; vs.x = spk2[0]; vs.y = spk2[1]; vs.z = spk2[2]; vs.w = spk2[3];
            *(vf4*)(o_spk2 + ((size_t)t * BATCH + b) * NO) = vs;
            if (storeMem) {
                vf4 vm; vm.x = m2[0]; vm.y = m2[1]; vm.z = m2[2]; vm.w = m2[3];
                *(vf4*)(o_mem2 + ((size_t)t * BATCH + b) * NO) = vm;
            }
        }
    }
}

// ---------------------------------------------------------------------------
// Launch 1: blocks 0..255 run the serial checkpoint scan; blocks 256..511
// emit chunk-0 outputs (no checkpoint dependency) CONCURRENTLY — the
// latency-bound scan hides under BW-bound stores. No intra-launch ordering
// needed: address sets are disjoint (chunk-0 skips its final mem rows).
// ---------------------------------------------------------------------------
__global__ __launch_bounds__(256, 2) void snn_front(
    const float* __restrict__ x, const float* __restrict__ W1,
    const float* __restrict__ b1, const float* __restrict__ W2,
    const float* __restrict__ b2, float* __restrict__ out)
{
    LOAD_WEIGHTS;
    if (blockIdx.x < BATCH / 256) {
        ckpt_body(blockIdx.x * 256 + threadIdx.x, x, w1, bb1, w2, bb2, out);
    } else {
        out_chunk(0, blockIdx.x - BATCH / 256, threadIdx.x, x, w1, bb1, w2, bb2, out);
    }
}

// ---------------------------------------------------------------------------
// Launch 2: chunks 1..9 (2304 blocks, ~16 waves/CU), replay from checkpoints.
// ---------------------------------------------------------------------------
__global__ __launch_bounds__(256, 4) void snn_rest(
    const float* __restrict__ x, const float* __restrict__ W1,
    const float* __restrict__ b1, const float* __restrict__ W2,
    const float* __restrict__ b2, float* __restrict__ out)
{
    LOAD_WEIGHTS;
    const int nbb = BATCH / 256;
    out_chunk(1 + blockIdx.x / nbb, blockIdx.x % nbb, threadIdx.x,
              x, w1, bb1, w2, bb2, out);
}

extern "C" void kernel_launch(void* const* d_in, const int* in_sizes, int n_in,
                              void* d_out, int out_size, void* d_ws, size_t ws_size,
                              hipStream_t stream) {
    const float* x  = (const float*)d_in[0];
    const float* W1 = (const float*)d_in[1];
    const float* b1 = (const float*)d_in[2];
    const float* W2 = (const float*)d_in[3];
    const float* b2 = (const float*)d_in[4];
    float* out = (float*)d_out;

    // Pass 1: checkpoint scan overlapped with chunk-0 output emission.
    snn_front<<<2 * (BATCH / 256), 256, 0, stream>>>(x, W1, b1, W2, b2, out);
    // Pass 2: chunks 1..9, time-parallel replay from checkpoints.
    snn_rest<<<(BATCH / 256) * (KCH - 1), 256, 0, stream>>>(x, W1, b1, W2, b2, out);
}